// Round 6
// baseline (193.853 us; speedup 1.0000x reference)
//
#include <hip/hip_runtime.h>

// FlashCRA on MI355X — round 6:
//  - attention v6: 2-wave blocks, each wave = one kv-half x 64 q-cols (2 q-sets).
//    K/V fragment reads shared across q-sets -> 2x MFMA per LDS byte. 4 blocks/CU.
//  - T1 XCD-chunked block remap on the GEMM grids (B-panel L2 locality).
//  - rest unchanged from round 5.

typedef __bf16 bf16;
typedef __bf16 bf16x8 __attribute__((ext_vector_type(8)));
typedef __bf16 bf16x4 __attribute__((ext_vector_type(4)));
typedef float f32x4 __attribute__((ext_vector_type(4)));
typedef float f32x16 __attribute__((ext_vector_type(16)));
typedef unsigned int u32;

__device__ __forceinline__ bf16 f2bf(float f) {
  unsigned u = __builtin_bit_cast(unsigned, f);
  u += 0x7FFFu + ((u >> 16) & 1u);            // RNE, inputs finite
  unsigned short h = (unsigned short)(u >> 16);
  return __builtin_bit_cast(bf16, h);
}

__device__ __forceinline__ void gload_lds16(const bf16* g, bf16* l) {
  __builtin_amdgcn_global_load_lds((const __attribute__((address_space(1))) u32*)(const void*)g,
                                   (__attribute__((address_space(3))) u32*)(void*)l, 16, 0, 0);
}

__device__ __forceinline__ u32 cvtpk_bf16(float lo, float hi) {
  u32 r;
  asm("v_cvt_pk_bf16_f32 %0, %1, %2" : "=v"(r) : "v"(lo), "v"(hi));
  return r;
}
__device__ __forceinline__ void perm32swap(u32& a, u32& b) {
  asm("v_permlane32_swap_b32 %0, %1" : "+v"(a), "+v"(b));
}

#if __has_builtin(__builtin_amdgcn_exp2f)
#define EXP2(x) __builtin_amdgcn_exp2f(x)
#else
#define EXP2(x) exp2f(x)
#endif

// SCALE * log2(e), folded into Q at pack time
#define QSCALE 0.18033688f

// XCD-chunked bijective remap (requires gridDim.x*gridDim.y % 8 == 0):
// consecutive remapped ids land on the same XCD and share the same by (B-panel).
__device__ __forceinline__ void xcd_remap(int& bx, int& by) {
  const int nx = gridDim.x;
  const int nwg = nx * gridDim.y;
  const int lin = blockIdx.y * nx + blockIdx.x;
  const int chunk = nwg >> 3;
  const int nid = (lin & 7) * chunk + (lin >> 3);
  bx = nid % nx;
  by = nid / nx;
}

// ---------------- fp32 -> bf16 elementwise ----------------
__global__ __launch_bounds__(256) void k_convert(const float* __restrict__ in,
                                                 bf16* __restrict__ out, int n4) {
  int i = blockIdx.x * 256 + threadIdx.x;
  if (i >= n4) return;
  const float4 v = ((const float4*)in)[i];
  bf16x4 o;
  o[0] = f2bf(v.x); o[1] = f2bf(v.y); o[2] = f2bf(v.z); o[3] = f2bf(v.w);
  *(bf16x4*)(out + (size_t)i * 4) = o;
}

// ---------------- fp32 [R][C] -> bf16 [C][R] ----------------
__global__ __launch_bounds__(256) void k_transpose(const float* __restrict__ in,
                                                   bf16* __restrict__ out, int R, int C) {
  __shared__ float t[64][65];
  int c0 = blockIdx.x * 64, r0 = blockIdx.y * 64;
  for (int e = threadIdx.x; e < 4096; e += 256) {
    int r = e >> 6, c = e & 63;
    t[r][c] = in[(size_t)(r0 + r) * C + c0 + c];
  }
  __syncthreads();
  for (int e = threadIdx.x; e < 4096; e += 256) {
    int c = e >> 6, r = e & 63;
    out[(size_t)(c0 + c) * R + r0 + r] = f2bf(t[r][c]);
  }
}

// ---------------- generic C[M][N] = A @ Bt^T + bias (m97 structure) ----------------
__global__ __launch_bounds__(256) void k_gemm128(const bf16* __restrict__ A,
                                                 const bf16* __restrict__ Bt,
                                                 const float* __restrict__ bias,
                                                 float* __restrict__ C,
                                                 int M, int N, int K) {
  __shared__ bf16 sA[128 * 64];
  __shared__ bf16 sB[128 * 64];
  const int tid = threadIdx.x;
  const int lane = tid & 63, w = tid >> 6;
  const int lrow = lane & 15, lgrp = lane >> 4;
  const int wm = (w >> 1) * 64, wn = (w & 1) * 64;
  int bx, by;
  xcd_remap(bx, by);
  const int m0 = bx * 128, n0 = by * 128;
  const int srow = tid >> 3, sslot = (tid & 7) * 8;

  f32x4 acc[4][4] = {};

  for (int k0 = 0; k0 < K; k0 += 64) {
#pragma unroll
    for (int i = 0; i < 4; ++i) {
      gload_lds16(A  + (size_t)(m0 + i * 32 + srow) * K + k0 + sslot, &sA[i * 2048 + w * 512]);
      gload_lds16(Bt + (size_t)(n0 + i * 32 + srow) * K + k0 + sslot, &sB[i * 2048 + w * 512]);
    }
    __syncthreads();
#pragma unroll
    for (int kk = 0; kk < 2; ++kk) {
      bf16x8 af[4], bff[4];
#pragma unroll
      for (int mi = 0; mi < 4; ++mi)
        af[mi] = *(const bf16x8*)&sA[(wm + mi * 16 + lrow) * 64 + kk * 32 + lgrp * 8];
#pragma unroll
      for (int ni = 0; ni < 4; ++ni)
        bff[ni] = *(const bf16x8*)&sB[(wn + ni * 16 + lrow) * 64 + kk * 32 + lgrp * 8];
      __builtin_amdgcn_s_setprio(1);
#pragma unroll
      for (int mi = 0; mi < 4; ++mi)
#pragma unroll
        for (int ni = 0; ni < 4; ++ni)
          acc[mi][ni] = __builtin_amdgcn_mfma_f32_16x16x32_bf16(af[mi], bff[ni], acc[mi][ni], 0, 0, 0);
      __builtin_amdgcn_s_setprio(0);
    }
    __syncthreads();
  }
#pragma unroll
  for (int mi = 0; mi < 4; ++mi)
#pragma unroll
    for (int ni = 0; ni < 4; ++ni) {
      const int col = n0 + wn + ni * 16 + lrow;
      const float bv = bias ? bias[col] : 0.f;
#pragma unroll
      for (int j = 0; j < 4; ++j) {
        const int row = m0 + wm + mi * 16 + lgrp * 4 + j;
        C[(size_t)row * N + col] = acc[mi][ni][j] + bv;
      }
    }
}

// ---------------- QKV GEMM with fused bias + rotation + pack epilogue ----------------
__global__ __launch_bounds__(256) void k_gemm_qkv(const bf16* __restrict__ A,
                                                  const bf16* __restrict__ Bt,
                                                  const float* __restrict__ bqkv,
                                                  const float* __restrict__ phases,
                                                  bf16* __restrict__ qb,
                                                  bf16* __restrict__ kb,
                                                  bf16* __restrict__ vb) {
  __shared__ bf16 sA[128 * 64];
  __shared__ bf16 sB[128 * 64];
  const int tid = threadIdx.x;
  const int lane = tid & 63, w = tid >> 6;
  const int lrow = lane & 15, lgrp = lane >> 4;
  const int wm = (w >> 1) * 64, wn = (w & 1) * 64;
  int bx, by;
  xcd_remap(bx, by);
  const int m0 = bx * 128, n0 = by * 128;
  const int srow = tid >> 3, sslot = (tid & 7) * 8;
  const int K = 1024;

  f32x4 acc[4][4] = {};

  for (int k0 = 0; k0 < K; k0 += 64) {
#pragma unroll
    for (int i = 0; i < 4; ++i) {
      gload_lds16(A  + (size_t)(m0 + i * 32 + srow) * K + k0 + sslot, &sA[i * 2048 + w * 512]);
      gload_lds16(Bt + (size_t)(n0 + i * 32 + srow) * K + k0 + sslot, &sB[i * 2048 + w * 512]);
    }
    __syncthreads();
#pragma unroll
    for (int kk = 0; kk < 2; ++kk) {
      bf16x8 af[4], bff[4];
#pragma unroll
      for (int mi = 0; mi < 4; ++mi)
        af[mi] = *(const bf16x8*)&sA[(wm + mi * 16 + lrow) * 64 + kk * 32 + lgrp * 8];
#pragma unroll
      for (int ni = 0; ni < 4; ++ni)
        bff[ni] = *(const bf16x8*)&sB[(wn + ni * 16 + lrow) * 64 + kk * 32 + lgrp * 8];
      __builtin_amdgcn_s_setprio(1);
#pragma unroll
      for (int mi = 0; mi < 4; ++mi)
#pragma unroll
        for (int ni = 0; ni < 4; ++ni)
          acc[mi][ni] = __builtin_amdgcn_mfma_f32_16x16x32_bf16(af[mi], bff[ni], acc[mi][ni], 0, 0, 0);
      __builtin_amdgcn_s_setprio(0);
    }
    __syncthreads();
  }

  // ---- epilogue ----
  const int sec = n0 >> 10;          // 0=q, 1=k, 2=v
  const int nn = n0 & 1023;
  const int hh = (nn + wn) >> 6;     // head for this wave
  const float b0 = bqkv[n0 + wn + lrow];
  const float b1 = bqkv[n0 + wn + 16 + lrow];
  const float b2 = bqkv[n0 + wn + 32 + lrow];
  const float b3 = bqkv[n0 + wn + 48 + lrow];

  if (sec == 2) {
#pragma unroll
    for (int mi = 0; mi < 4; ++mi) {
      const int row0 = m0 + wm + mi * 16 + lgrp * 4;
      const int b = row0 >> 11, l0 = row0 & 2047;
#pragma unroll
      for (int ni = 0; ni < 4; ++ni) {
        const int d = ni * 16 + lrow;
        const float bv = (ni == 0) ? b0 : (ni == 1) ? b1 : (ni == 2) ? b2 : b3;
        bf16x4 pv;
#pragma unroll
        for (int j = 0; j < 4; ++j) pv[j] = f2bf(acc[mi][ni][j] + bv);
        *(bf16x4*)&vb[(((size_t)(b * 16 + hh)) * 64 + d) * 2048 + l0] = pv;
      }
    }
  } else {
    bf16* qk = sec ? kb : qb;
    const float qs = sec ? 1.0f : QSCALE;
#pragma unroll
    for (int mi = 0; mi < 4; ++mi) {
#pragma unroll
      for (int j = 0; j < 4; ++j) {
        const int row = m0 + wm + mi * 16 + lgrp * 4 + j;
        const int b = row >> 11, l = row & 2047;
        const float ph1 = phases[(size_t)row * 512 + hh * 32 + lrow];
        const float ph2 = phases[(size_t)row * 512 + hh * 32 + 16 + lrow];
        float s1, c1, s2, c2;
        __sincosf(ph1, &s1, &c1);
        __sincosf(ph2, &s2, &c2);
        const float t0 = acc[mi][0][j] + b0;
        const float t1 = acc[mi][1][j] + b1;
        const float t2 = acc[mi][2][j] + b2;
        const float t3 = acc[mi][3][j] + b3;
        bf16* base = qk + (((size_t)(b * 16 + hh)) * 2048 + l) * 64;
        base[lrow]      = f2bf((t0 * c1 - t2 * s1) * qs);
        base[16 + lrow] = f2bf((t1 * c2 - t3 * s2) * qs);
        base[32 + lrow] = f2bf((t0 * s1 + t2 * c1) * qs);
        base[48 + lrow] = f2bf((t1 * s2 + t3 * c2) * qs);
      }
    }
  }
}

// ---------------- flash attention v6: 2-wave blocks, kv-half x 64q per wave ----------------
// Wave w = kv rows w*32..w*32+31 of every tile; covers 64 q-cols via 2 q-sets.
// K/V fragment reads shared across q-sets: 8 b128 reads per 16 MFMA per tile.
// No-max softmax (additive partials); LDS combine of the 2 kv-half partials.
__global__ __launch_bounds__(128, 2) void k_flash_attn6(const bf16* __restrict__ qb,
                                                        const bf16* __restrict__ kb,
                                                        const bf16* __restrict__ vb,
                                                        bf16* __restrict__ attnout) {
  const int tid = threadIdx.x, lane = tid & 63, w = tid >> 6;   // w = kv half
  const int ql = lane & 31, hi = lane >> 5;
  // XCD-aware swizzle: 128 consecutive nids per XCD (one (b,h)'s K/V L2-resident)
  const int fid = blockIdx.x;
  const int nid = (fid & 7) * 128 + (fid >> 3);
  const int qblk = nid & 31, h = (nid >> 5) & 15, b = nid >> 9;
  const size_t bh = (size_t)b * 16 + h;
  const bf16* Kp = kb + bh * 2048 * 64;
  const bf16* Vp = vb + bh * 64 * 2048;

  __shared__ __align__(16) char smem[32768];
  bf16* sK = (bf16*)smem;                      // [2][64*64] dbuf
  bf16* sV = (bf16*)(smem + 16384);

  // Q fragments for both q-sets (cols qblk*64 + qs*32 + ql)
  bf16x8 qf[2][4];
#pragma unroll
  for (int qs = 0; qs < 2; ++qs) {
    const bf16* Qp = qb + (bh * 2048 + (size_t)qblk * 64 + qs * 32 + ql) * 64;
#pragma unroll
    for (int c = 0; c < 4; ++c) qf[qs][c] = *(const bf16x8*)(Qp + c * 16 + hi * 8);
  }

  const int srow = tid >> 3;                   // 0..15
  const int slot = tid & 7;
  const int swz = slot ^ (srow & 7);           // pre-swizzled global 16B slot (key = row&7)

  f32x16 o00 = {}, o01 = {}, o10 = {}, o11 = {};
  float lsum0 = 0.f, lsum1 = 0.f;

  // 8 gload_lds per tile pair: K rows srow+{0,16,32,48}, V rows (=d) same offsets
#define STAGE(BUF, KV0)                                                                         \
  do {                                                                                          \
    gload_lds16(Kp + (size_t)((KV0) + srow) * 64 + swz * 8,        sK + (BUF) * 4096 + w * 512);         \
    gload_lds16(Kp + (size_t)((KV0) + 16 + srow) * 64 + swz * 8,   sK + (BUF) * 4096 + 1024 + w * 512);  \
    gload_lds16(Kp + (size_t)((KV0) + 32 + srow) * 64 + swz * 8,   sK + (BUF) * 4096 + 2048 + w * 512);  \
    gload_lds16(Kp + (size_t)((KV0) + 48 + srow) * 64 + swz * 8,   sK + (BUF) * 4096 + 3072 + w * 512);  \
    gload_lds16(Vp + (size_t)srow * 2048 + (KV0) + swz * 8,        sV + (BUF) * 4096 + w * 512);         \
    gload_lds16(Vp + (size_t)(16 + srow) * 2048 + (KV0) + swz * 8, sV + (BUF) * 4096 + 1024 + w * 512);  \
    gload_lds16(Vp + (size_t)(32 + srow) * 2048 + (KV0) + swz * 8, sV + (BUF) * 4096 + 2048 + w * 512);  \
    gload_lds16(Vp + (size_t)(48 + srow) * 2048 + (KV0) + swz * 8, sV + (BUF) * 4096 + 3072 + w * 512);  \
  } while (0)

  STAGE(0, 0);
  __syncthreads();

  for (int t = 0; t < 32; ++t) {
    const int cur = t & 1;
    if (t < 31) STAGE(cur ^ 1, (t + 1) * 64);

    const bf16* sKc = sK + cur * 4096;
    const bf16* sVc = sV + cur * 4096;

    // ---- QK^T for both q-sets; kf shared ----
    f32x16 st0 = {}, st1 = {};
#pragma unroll
    for (int c = 0; c < 4; ++c) {
      const int j = (c * 2 + hi) ^ (ql & 7);
      bf16x8 kf = *(const bf16x8*)&sKc[(w * 32 + ql) * 64 + j * 8];
      __builtin_amdgcn_s_setprio(1);
      st0 = __builtin_amdgcn_mfma_f32_32x32x16_bf16(kf, qf[0][c], st0, 0, 0, 0);
      st1 = __builtin_amdgcn_mfma_f32_32x32x16_bf16(kf, qf[1][c], st1, 0, 0, 0);
      __builtin_amdgcn_s_setprio(0);
    }

    // ---- no-max softmax: P = exp2(S) (scale folded into Q) ----
    float rs0 = 0.f, rs1 = 0.f;
#pragma unroll
    for (int j2 = 0; j2 < 16; ++j2) {
      float p0 = EXP2(st0[j2]); st0[j2] = p0; rs0 += p0;
      float p1 = EXP2(st1[j2]); st1[j2] = p1; rs1 += p1;
    }
    rs0 += __shfl_xor(rs0, 32); lsum0 += rs0;
    rs1 += __shfl_xor(rs1, 32); lsum1 += rs1;

    // ---- P -> bf16, PV; vf shared across q-sets ----
#pragma unroll
    for (int fs = 0; fs < 2; ++fs) {
      u32 a0 = cvtpk_bf16(st0[fs * 8 + 0], st0[fs * 8 + 1]);
      u32 a1 = cvtpk_bf16(st0[fs * 8 + 2], st0[fs * 8 + 3]);
      u32 a2 = cvtpk_bf16(st0[fs * 8 + 4], st0[fs * 8 + 5]);
      u32 a3 = cvtpk_bf16(st0[fs * 8 + 6], st0[fs * 8 + 7]);
      perm32swap(a0, a2); perm32swap(a1, a3);
      union { u32 u[4]; bf16x8 v; } cuA;
      cuA.u[0] = a0; cuA.u[1] = a1; cuA.u[2] = a2; cuA.u[3] = a3;
      u32 b0 = cvtpk_bf16(st1[fs * 8 + 0], st1[fs * 8 + 1]);
      u32 b1 = cvtpk_bf16(st1[fs * 8 + 2], st1[fs * 8 + 3]);
      u32 b2 = cvtpk_bf16(st1[fs * 8 + 4], st1[fs * 8 + 5]);
      u32 b3 = cvtpk_bf16(st1[fs * 8 + 6], st1[fs * 8 + 7]);
      perm32swap(b0, b2); perm32swap(b1, b3);
      union { u32 u[4]; bf16x8 v; } cuB;
      cuB.u[0] = b0; cuB.u[1] = b1; cuB.u[2] = b2; cuB.u[3] = b3;

      const int j = (w * 4 + fs * 2 + hi) ^ (ql & 7);
      bf16x8 vf0 = *(const bf16x8*)&sVc[ql * 64 + j * 8];
      bf16x8 vf1 = *(const bf16x8*)&sVc[(32 + ql) * 64 + j * 8];
      __builtin_amdgcn_s_setprio(1);
      o00 = __builtin_amdgcn_mfma_f32_32x32x16_bf16(vf0, cuA.v, o00, 0, 0, 0);
      o01 = __builtin_amdgcn_mfma_f32_32x32x16_bf16(vf1, cuA.v, o01, 0, 0, 0);
      o10 = __builtin_amdgcn_mfma_f32_32x32x16_bf16(vf0, cuB.v, o10, 0, 0, 0);
      o11 = __builtin_amdgcn_mfma_f32_32x32x16_bf16(vf1, cuB.v, o11, 0, 0, 0);
      __builtin_amdgcn_s_setprio(0);
    }
    __syncthreads();
  }

  // ---- combine kv-half partials (wave 1 -> LDS, wave 0 adds + writes) ----
  float* cb = (float*)smem;                    // 64 lanes * 66 f32 = 16.9 KB
  if (w == 1) {
    const int idx = lane * 66;
#pragma unroll
    for (int i = 0; i < 16; ++i) { cb[idx + i] = o00[i]; cb[idx + 16 + i] = o01[i]; }
    cb[idx + 32] = lsum0;
#pragma unroll
    for (int i = 0; i < 16; ++i) { cb[idx + 33 + i] = o10[i]; cb[idx + 49 + i] = o11[i]; }
    cb[idx + 65] = lsum1;
  }
  __syncthreads();
  if (w == 0) {
    const int idx = lane * 66;
#pragma unroll
    for (int i = 0; i < 16; ++i) { o00[i] += cb[idx + i]; o01[i] += cb[idx + 16 + i]; }
    lsum0 += cb[idx + 32];
#pragma unroll
    for (int i = 0; i < 16; ++i) { o10[i] += cb[idx + 33 + i]; o11[i] += cb[idx + 49 + i]; }
    lsum1 += cb[idx + 65];

    const float inv0 = 1.f / lsum0;
    const float inv1 = 1.f / lsum1;
    const int qrow0 = qblk * 64 + ql;
    bf16* outp0 = attnout + ((size_t)b * 2048 + qrow0) * 1024 + h * 64;
    bf16* outp1 = attnout + ((size_t)b * 2048 + qrow0 + 32) * 1024 + h * 64;
#pragma unroll
    for (int j2 = 0; j2 < 4; ++j2) {
      bf16x4 ov;
#pragma unroll
      for (int jj = 0; jj < 4; ++jj) ov[jj] = f2bf(o00[j2 * 4 + jj] * inv0);
      *(bf16x4*)(outp0 + j2 * 8 + hi * 4) = ov;
#pragma unroll
      for (int jj = 0; jj < 4; ++jj) ov[jj] = f2bf(o01[j2 * 4 + jj] * inv0);
      *(bf16x4*)(outp0 + 32 + j2 * 8 + hi * 4) = ov;
#pragma unroll
      for (int jj = 0; jj < 4; ++jj) ov[jj] = f2bf(o10[j2 * 4 + jj] * inv1);
      *(bf16x4*)(outp1 + j2 * 8 + hi * 4) = ov;
#pragma unroll
      for (int jj = 0; jj < 4; ++jj) ov[jj] = f2bf(o11[j2 * 4 + jj] * inv1);
      *(bf16x4*)(outp1 + 32 + j2 * 8 + hi * 4) = ov;
    }
  }
#undef STAGE
}

// ---------------- launch ----------------
extern "C" void kernel_launch(void* const* d_in, const int* in_sizes, int n_in,
                              void* d_out, int out_size, void* d_ws, size_t ws_size,
                              hipStream_t stream) {
  (void)in_sizes; (void)n_in; (void)out_size; (void)ws_size;
  const float* x    = (const float*)d_in[0];
  const float* p    = (const float*)d_in[1];
  const float* Wqkv = (const float*)d_in[2];
  const float* bqkv = (const float*)d_in[3];
  const float* Wout = (const float*)d_in[4];
  const float* bout = (const float*)d_in[5];
  const float* proj = (const float*)d_in[6];
  float* out = (float*)d_out;

  char* ws = (char*)d_ws;
  size_t off = 0;
  bf16* xb     = (bf16*)(ws + off); off += (size_t)4096 * 1024 * 2;
  bf16* pb     = (bf16*)(ws + off); off += (size_t)4096 * 1024 * 2;
  bf16* WqkvT  = (bf16*)(ws + off); off += (size_t)3072 * 1024 * 2;
  bf16* projT  = (bf16*)(ws + off); off += (size_t)512  * 1024 * 2;
  bf16* WoutT  = (bf16*)(ws + off); off += (size_t)1024 * 1024 * 2;
  float* phases= (float*)(ws + off); off += (size_t)4096 * 512 * 4;
  bf16* qb     = (bf16*)(ws + off); off += (size_t)4096 * 1024 * 2;
  bf16* kb     = (bf16*)(ws + off); off += (size_t)4096 * 1024 * 2;
  bf16* vb     = (bf16*)(ws + off); off += (size_t)4096 * 1024 * 2;
  bf16* attnb  = (bf16*)(ws + off); off += (size_t)4096 * 1024 * 2;

  k_convert<<<4096, 256, 0, stream>>>(x, xb, 1048576);
  k_convert<<<4096, 256, 0, stream>>>(p, pb, 1048576);
  k_transpose<<<dim3(48, 16), 256, 0, stream>>>(Wqkv, WqkvT, 1024, 3072);
  k_transpose<<<dim3(8, 16),  256, 0, stream>>>(proj, projT, 1024, 512);
  k_transpose<<<dim3(16, 16), 256, 0, stream>>>(Wout, WoutT, 1024, 1024);

  k_gemm128<<<dim3(32, 4), 256, 0, stream>>>(pb, projT, nullptr, phases, 4096, 512, 1024);
  k_gemm_qkv<<<dim3(32, 24), 256, 0, stream>>>(xb, WqkvT, bqkv, phases, qb, kb, vb);

  k_flash_attn6<<<1024, 128, 0, stream>>>(qb, kb, vb, attnb);

  k_gemm128<<<dim3(32, 8), 256, 0, stream>>>(attnb, WoutT, bout, out, 4096, 1024, 1024);
}

// Round 7
// 162.428 us; speedup vs baseline: 1.1935x; 1.1935x over previous
//
#include <hip/hip_runtime.h>

// FlashCRA on MI355X — round 7:
//  - attention REVERTED to round-5 kernel (proven ~49us; v6's 2-wave config was latency-bound).
//  - qkv GEMM -> 256x256 tile, 8 waves, spread-issue staging with tile-boundary wait only
//    (counted-vmcnt-style overlap), T2 XOR swizzle on LDS, B-frags register-held.
//  - phase/out GEMMs stay 128x128 (k_gemm128 + XCD remap).

typedef __bf16 bf16;
typedef __bf16 bf16x8 __attribute__((ext_vector_type(8)));
typedef __bf16 bf16x4 __attribute__((ext_vector_type(4)));
typedef float f32x4 __attribute__((ext_vector_type(4)));
typedef float f32x16 __attribute__((ext_vector_type(16)));
typedef unsigned int u32;

__device__ __forceinline__ bf16 f2bf(float f) {
  unsigned u = __builtin_bit_cast(unsigned, f);
  u += 0x7FFFu + ((u >> 16) & 1u);            // RNE, inputs finite
  unsigned short h = (unsigned short)(u >> 16);
  return __builtin_bit_cast(bf16, h);
}

__device__ __forceinline__ void gload_lds16(const bf16* g, bf16* l) {
  __builtin_amdgcn_global_load_lds((const __attribute__((address_space(1))) u32*)(const void*)g,
                                   (__attribute__((address_space(3))) u32*)(void*)l, 16, 0, 0);
}

__device__ __forceinline__ u32 cvtpk_bf16(float lo, float hi) {
  u32 r;
  asm("v_cvt_pk_bf16_f32 %0, %1, %2" : "=v"(r) : "v"(lo), "v"(hi));
  return r;
}
__device__ __forceinline__ void perm32swap(u32& a, u32& b) {
  asm("v_permlane32_swap_b32 %0, %1" : "+v"(a), "+v"(b));
}

#if __has_builtin(__builtin_amdgcn_exp2f)
#define EXP2(x) __builtin_amdgcn_exp2f(x)
#else
#define EXP2(x) exp2f(x)
#endif

// SCALE * log2(e), folded into Q at pack time
#define QSCALE 0.18033688f

// XCD-chunked bijective remap (requires gridDim.x*gridDim.y % 8 == 0)
__device__ __forceinline__ void xcd_remap(int& bx, int& by) {
  const int nx = gridDim.x;
  const int nwg = nx * gridDim.y;
  const int lin = blockIdx.y * nx + blockIdx.x;
  const int chunk = nwg >> 3;
  const int nid = (lin & 7) * chunk + (lin >> 3);
  bx = nid % nx;
  by = nid / nx;
}

// ---------------- fp32 -> bf16 elementwise ----------------
__global__ __launch_bounds__(256) void k_convert(const float* __restrict__ in,
                                                 bf16* __restrict__ out, int n4) {
  int i = blockIdx.x * 256 + threadIdx.x;
  if (i >= n4) return;
  const float4 v = ((const float4*)in)[i];
  bf16x4 o;
  o[0] = f2bf(v.x); o[1] = f2bf(v.y); o[2] = f2bf(v.z); o[3] = f2bf(v.w);
  *(bf16x4*)(out + (size_t)i * 4) = o;
}

// ---------------- fp32 [R][C] -> bf16 [C][R] ----------------
__global__ __launch_bounds__(256) void k_transpose(const float* __restrict__ in,
                                                   bf16* __restrict__ out, int R, int C) {
  __shared__ float t[64][65];
  int c0 = blockIdx.x * 64, r0 = blockIdx.y * 64;
  for (int e = threadIdx.x; e < 4096; e += 256) {
    int r = e >> 6, c = e & 63;
    t[r][c] = in[(size_t)(r0 + r) * C + c0 + c];
  }
  __syncthreads();
  for (int e = threadIdx.x; e < 4096; e += 256) {
    int c = e >> 6, r = e & 63;
    out[(size_t)(c0 + c) * R + r0 + r] = f2bf(t[r][c]);
  }
}

// ---------------- generic C[M][N] = A @ Bt^T + bias (m97 structure) ----------------
__global__ __launch_bounds__(256) void k_gemm128(const bf16* __restrict__ A,
                                                 const bf16* __restrict__ Bt,
                                                 const float* __restrict__ bias,
                                                 float* __restrict__ C,
                                                 int M, int N, int K) {
  __shared__ bf16 sA[128 * 64];
  __shared__ bf16 sB[128 * 64];
  const int tid = threadIdx.x;
  const int lane = tid & 63, w = tid >> 6;
  const int lrow = lane & 15, lgrp = lane >> 4;
  const int wm = (w >> 1) * 64, wn = (w & 1) * 64;
  int bx, by;
  xcd_remap(bx, by);
  const int m0 = bx * 128, n0 = by * 128;
  const int srow = tid >> 3, sslot = (tid & 7) * 8;

  f32x4 acc[4][4] = {};

  for (int k0 = 0; k0 < K; k0 += 64) {
#pragma unroll
    for (int i = 0; i < 4; ++i) {
      gload_lds16(A  + (size_t)(m0 + i * 32 + srow) * K + k0 + sslot, &sA[i * 2048 + w * 512]);
      gload_lds16(Bt + (size_t)(n0 + i * 32 + srow) * K + k0 + sslot, &sB[i * 2048 + w * 512]);
    }
    __syncthreads();
#pragma unroll
    for (int kk = 0; kk < 2; ++kk) {
      bf16x8 af[4], bff[4];
#pragma unroll
      for (int mi = 0; mi < 4; ++mi)
        af[mi] = *(const bf16x8*)&sA[(wm + mi * 16 + lrow) * 64 + kk * 32 + lgrp * 8];
#pragma unroll
      for (int ni = 0; ni < 4; ++ni)
        bff[ni] = *(const bf16x8*)&sB[(wn + ni * 16 + lrow) * 64 + kk * 32 + lgrp * 8];
      __builtin_amdgcn_s_setprio(1);
#pragma unroll
      for (int mi = 0; mi < 4; ++mi)
#pragma unroll
        for (int ni = 0; ni < 4; ++ni)
          acc[mi][ni] = __builtin_amdgcn_mfma_f32_16x16x32_bf16(af[mi], bff[ni], acc[mi][ni], 0, 0, 0);
      __builtin_amdgcn_s_setprio(0);
    }
    __syncthreads();
  }
#pragma unroll
  for (int mi = 0; mi < 4; ++mi)
#pragma unroll
    for (int ni = 0; ni < 4; ++ni) {
      const int col = n0 + wn + ni * 16 + lrow;
      const float bv = bias ? bias[col] : 0.f;
#pragma unroll
      for (int j = 0; j < 4; ++j) {
        const int row = m0 + wm + mi * 16 + lgrp * 4 + j;
        C[(size_t)row * N + col] = acc[mi][ni][j] + bv;
      }
    }
}

// ---------------- QKV GEMM, 256x256 tile, spread-issue staging + fused rotate ----------------
// 512 thr = 8 waves (2M x 4N); per-wave 128x64 output = acc[8][4] 16x16 frags.
// LDS 128KB: A/B double-buffered 256x64 bf16, XOR-swizzled (source-side for gload_lds,
// matching XOR on ds_read). Stages for tile kt+1 issued during kt's 4 phases; single
// tile-boundary __syncthreads (vmcnt drain) per K-tile -> issue-to-wait ~ full tile.
__global__ __launch_bounds__(512, 2) void k_gemm_qkv256(const bf16* __restrict__ A,
                                                        const bf16* __restrict__ Bt,
                                                        const float* __restrict__ bqkv,
                                                        const float* __restrict__ phases,
                                                        bf16* __restrict__ qb,
                                                        bf16* __restrict__ kb,
                                                        bf16* __restrict__ vb) {
  __shared__ bf16 sA0[16384], sA1[16384];     // 256 x 64 each
  __shared__ bf16 sB0[16384], sB1[16384];
  const int tid = threadIdx.x;
  const int lane = tid & 63, w = tid >> 6;
  const int lrow = lane & 15, lgrp = lane >> 4;
  const int wm = (w >> 2) * 128;              // wave M offset: 0 / 128
  const int wn = (w & 3) * 64;                // wave N offset: 0..192
  const int m0 = blockIdx.x * 256, n0 = blockIdx.y * 256;
  const int K = 1024;

  // staging: lane l of wave w covers row g*64 + w*8 + (l>>3), swizzled 16B slot
  const int srow = tid >> 3;                  // 0..63
  const int swz8 = (((tid & 7) ^ (srow & 7))) * 8;
  const int r7 = lrow & 7;                    // ds_read swizzle key (row&7 == lrow&7 here)

  const bf16* Ab = A  + (size_t)m0 * K;
  const bf16* Bb = Bt + (size_t)n0 * K;

  f32x4 acc[8][4] = {};

  // prologue: stage tile 0 into buf0
#pragma unroll
  for (int g = 0; g < 4; ++g) {
    gload_lds16(Ab + (size_t)(g * 64 + srow) * K + swz8, sA0 + g * 4096 + w * 512);
    gload_lds16(Bb + (size_t)(g * 64 + srow) * K + swz8, sB0 + g * 4096 + w * 512);
  }
  __syncthreads();

  for (int kt = 0; kt < 16; ++kt) {
    const bf16* pA = (kt & 1) ? sA1 : sA0;
    const bf16* pB = (kt & 1) ? sB1 : sB0;
    bf16* nA = (kt & 1) ? sA0 : sA1;
    bf16* nB = (kt & 1) ? sB0 : sB1;
    const size_t knext = (size_t)(kt + 1) * 64;

    // B fragments for the whole tile, held in registers across the 4 phases
    bf16x8 bfr[4][2];
#pragma unroll
    for (int ni = 0; ni < 4; ++ni)
#pragma unroll
      for (int kk = 0; kk < 2; ++kk)
        bfr[ni][kk] = *(const bf16x8*)&pB[(wn + ni * 16 + lrow) * 64 + ((kk * 4 + lgrp) ^ r7) * 8];

#pragma unroll
    for (int q = 0; q < 4; ++q) {
      if (kt < 15) {
        gload_lds16(Ab + (size_t)(q * 64 + srow) * K + knext + swz8, nA + q * 4096 + w * 512);
        gload_lds16(Bb + (size_t)(q * 64 + srow) * K + knext + swz8, nB + q * 4096 + w * 512);
      }
      bf16x8 af[2][2];
#pragma unroll
      for (int m2 = 0; m2 < 2; ++m2)
#pragma unroll
        for (int kk = 0; kk < 2; ++kk)
          af[m2][kk] = *(const bf16x8*)&pA[(wm + (q * 2 + m2) * 16 + lrow) * 64 + ((kk * 4 + lgrp) ^ r7) * 8];
      __builtin_amdgcn_s_setprio(1);
#pragma unroll
      for (int m2 = 0; m2 < 2; ++m2)
#pragma unroll
        for (int ni = 0; ni < 4; ++ni)
#pragma unroll
          for (int kk = 0; kk < 2; ++kk)
            acc[q * 2 + m2][ni] =
                __builtin_amdgcn_mfma_f32_16x16x32_bf16(af[m2][kk], bfr[ni][kk], acc[q * 2 + m2][ni], 0, 0, 0);
      __builtin_amdgcn_s_setprio(0);
    }
    __syncthreads();   // drains vmcnt (next tile staged) + orders WAR for the buffer swap
  }

  // ---- fused epilogue: bias + rotate + pack (extension of proven 128^2 epilogue) ----
  const int nw = n0 + wn;            // wave's 64-col base; whole wave in one section/head
  const int sec = nw >> 10;          // 0=q, 1=k, 2=v
  const int hh = (nw & 1023) >> 6;
  const float b0 = bqkv[nw + lrow];
  const float b1 = bqkv[nw + 16 + lrow];
  const float b2 = bqkv[nw + 32 + lrow];
  const float b3 = bqkv[nw + 48 + lrow];

  if (sec == 2) {
#pragma unroll
    for (int mi = 0; mi < 8; ++mi) {
      const int row0 = m0 + wm + mi * 16 + lgrp * 4;
      const int b = row0 >> 11, l0 = row0 & 2047;
#pragma unroll
      for (int ni = 0; ni < 4; ++ni) {
        const int d = ni * 16 + lrow;
        const float bv = (ni == 0) ? b0 : (ni == 1) ? b1 : (ni == 2) ? b2 : b3;
        bf16x4 pv;
#pragma unroll
        for (int j = 0; j < 4; ++j) pv[j] = f2bf(acc[mi][ni][j] + bv);
        *(bf16x4*)&vb[(((size_t)(b * 16 + hh)) * 64 + d) * 2048 + l0] = pv;
      }
    }
  } else {
    bf16* qk = sec ? kb : qb;
    const float qs = sec ? 1.0f : QSCALE;
#pragma unroll
    for (int mi = 0; mi < 8; ++mi) {
#pragma unroll
      for (int j = 0; j < 4; ++j) {
        const int row = m0 + wm + mi * 16 + lgrp * 4 + j;
        const int b = row >> 11, l = row & 2047;
        const float ph1 = phases[(size_t)row * 512 + hh * 32 + lrow];
        const float ph2 = phases[(size_t)row * 512 + hh * 32 + 16 + lrow];
        float s1, c1, s2, c2;
        __sincosf(ph1, &s1, &c1);
        __sincosf(ph2, &s2, &c2);
        const float t0 = acc[mi][0][j] + b0;
        const float t1 = acc[mi][1][j] + b1;
        const float t2 = acc[mi][2][j] + b2;
        const float t3 = acc[mi][3][j] + b3;
        bf16* base = qk + (((size_t)(b * 16 + hh)) * 2048 + l) * 64;
        base[lrow]      = f2bf((t0 * c1 - t2 * s1) * qs);
        base[16 + lrow] = f2bf((t1 * c2 - t3 * s2) * qs);
        base[32 + lrow] = f2bf((t0 * s1 + t2 * c1) * qs);
        base[48 + lrow] = f2bf((t1 * s2 + t3 * c2) * qs);
      }
    }
  }
}

// ---------------- flash attention (round-5 kernel, reverted verbatim) ----------------
__global__ __launch_bounds__(256, 4) void k_flash_attn5(const bf16* __restrict__ qb,
                                                        const bf16* __restrict__ kb,
                                                        const bf16* __restrict__ vb,
                                                        bf16* __restrict__ attnout) {
  const int tid = threadIdx.x, lane = tid & 63, w = tid >> 6;
  const int ql = lane & 31, hi = lane >> 5;
  const int tsel = w >> 1;                    // kv half of tile
  const int qh = w & 1;                       // q half (32 rows)
  const int fid = blockIdx.x;
  const int nid = (fid & 7) * 128 + (fid >> 3);
  const int qblk = nid & 31, h = (nid >> 5) & 15, b = nid >> 9;
  const size_t bh = (size_t)b * 16 + h;
  const bf16* Kp = kb + bh * 2048 * 64;
  const bf16* Vp = vb + bh * 64 * 2048;

  __shared__ __align__(16) char smem[32768];
  bf16* sK = (bf16*)smem;                     // [2][64*64] double-buffered
  bf16* sV = (bf16*)(smem + 16384);

  const bf16* Qp = qb + (bh * 2048 + (size_t)qblk * 64 + qh * 32 + ql) * 64;
  bf16x8 qf[4];
#pragma unroll
  for (int c = 0; c < 4; ++c) qf[c] = *(const bf16x8*)(Qp + c * 16 + hi * 8);

  const int srow = tid >> 3;                  // 0..31
  const int swz = (tid & 7) ^ (srow & 7);     // pre-swizzled global 16B slot

  f32x16 o0 = {}, o1 = {};
  float lsum = 0.f;

#define STAGE(BUF, KV0)                                                                       \
  do {                                                                                        \
    gload_lds16(Kp + (size_t)((KV0) + srow) * 64 + swz * 8,        sK + (BUF) * 4096 + w * 512); \
    gload_lds16(Kp + (size_t)((KV0) + srow + 32) * 64 + swz * 8,   sK + (BUF) * 4096 + 2048 + w * 512); \
    gload_lds16(Vp + (size_t)srow * 2048 + (KV0) + swz * 8,        sV + (BUF) * 4096 + w * 512); \
    gload_lds16(Vp + (size_t)(srow + 32) * 2048 + (KV0) + swz * 8, sV + (BUF) * 4096 + 2048 + w * 512); \
  } while (0)

  STAGE(0, 0);
  __syncthreads();

  for (int t = 0; t < 32; ++t) {
    const int cur = t & 1;
    if (t < 31) STAGE(cur ^ 1, (t + 1) * 64);

    const bf16* sKc = sK + cur * 4096;
    const bf16* sVc = sV + cur * 4096;

    f32x16 st0 = {};
#pragma unroll
    for (int c = 0; c < 4; ++c) {
      const int j = (c * 2 + hi) ^ (ql & 7);
      bf16x8 kf = *(const bf16x8*)&sKc[(tsel * 32 + ql) * 64 + j * 8];
      __builtin_amdgcn_s_setprio(1);
      st0 = __builtin_amdgcn_mfma_f32_32x32x16_bf16(kf, qf[c], st0, 0, 0, 0);
      __builtin_amdgcn_s_setprio(0);
    }

    float rs = 0.f;
#pragma unroll
    for (int j2 = 0; j2 < 16; ++j2) {
      float pv = EXP2(st0[j2]);
      st0[j2] = pv; rs += pv;
    }
    rs += __shfl_xor(rs, 32);
    lsum += rs;

#pragma unroll
    for (int fs = 0; fs < 2; ++fs) {
      u32 a0 = cvtpk_bf16(st0[fs * 8 + 0], st0[fs * 8 + 1]);
      u32 a1 = cvtpk_bf16(st0[fs * 8 + 2], st0[fs * 8 + 3]);
      u32 a2 = cvtpk_bf16(st0[fs * 8 + 4], st0[fs * 8 + 5]);
      u32 a3 = cvtpk_bf16(st0[fs * 8 + 6], st0[fs * 8 + 7]);
      perm32swap(a0, a2);
      perm32swap(a1, a3);
      union { u32 u[4]; bf16x8 v; } cu;
      cu.u[0] = a0; cu.u[1] = a1; cu.u[2] = a2; cu.u[3] = a3;
      const int j = (tsel * 4 + fs * 2 + hi) ^ (ql & 7);
      bf16x8 vf0 = *(const bf16x8*)&sVc[ql * 64 + j * 8];
      bf16x8 vf1 = *(const bf16x8*)&sVc[(32 + ql) * 64 + j * 8];
      __builtin_amdgcn_s_setprio(1);
      o0 = __builtin_amdgcn_mfma_f32_32x32x16_bf16(vf0, cu.v, o0, 0, 0, 0);
      o1 = __builtin_amdgcn_mfma_f32_32x32x16_bf16(vf1, cu.v, o1, 0, 0, 0);
      __builtin_amdgcn_s_setprio(0);
    }
    __syncthreads();
  }

  float* cb = (float*)smem;
  if (w >= 2) {
    const int idx = ((w - 2) * 64 + lane) * 34;
#pragma unroll
    for (int i = 0; i < 16; ++i) cb[idx + i] = o0[i];
#pragma unroll
    for (int i = 0; i < 16; ++i) cb[idx + 16 + i] = o1[i];
    cb[idx + 32] = lsum;
  }
  __syncthreads();
  if (w < 2) {
    const int idx = (w * 64 + lane) * 34;
#pragma unroll
    for (int i = 0; i < 16; ++i) o0[i] += cb[idx + i];
#pragma unroll
    for (int i = 0; i < 16; ++i) o1[i] += cb[idx + 16 + i];
    lsum += cb[idx + 32];

    const float inv = 1.f / lsum;
    const int qrow = qblk * 64 + qh * 32 + ql;
    bf16* outp = attnout + ((size_t)b * 2048 + qrow) * 1024 + h * 64;
#pragma unroll
    for (int j2 = 0; j2 < 4; ++j2) {
      bf16x4 ov;
#pragma unroll
      for (int jj = 0; jj < 4; ++jj) ov[jj] = f2bf(o0[j2 * 4 + jj] * inv);
      *(bf16x4*)(outp + j2 * 8 + hi * 4) = ov;
#pragma unroll
      for (int jj = 0; jj < 4; ++jj) ov[jj] = f2bf(o1[j2 * 4 + jj] * inv);
      *(bf16x4*)(outp + 32 + j2 * 8 + hi * 4) = ov;
    }
  }
#undef STAGE
}

// ---------------- launch ----------------
extern "C" void kernel_launch(void* const* d_in, const int* in_sizes, int n_in,
                              void* d_out, int out_size, void* d_ws, size_t ws_size,
                              hipStream_t stream) {
  (void)in_sizes; (void)n_in; (void)out_size; (void)ws_size;
  const float* x    = (const float*)d_in[0];
  const float* p    = (const float*)d_in[1];
  const float* Wqkv = (const float*)d_in[2];
  const float* bqkv = (const float*)d_in[3];
  const float* Wout = (const float*)d_in[4];
  const float* bout = (const float*)d_in[5];
  const float* proj = (const float*)d_in[6];
  float* out = (float*)d_out;

  char* ws = (char*)d_ws;
  size_t off = 0;
  bf16* xb     = (bf16*)(ws + off); off += (size_t)4096 * 1024 * 2;
  bf16* pb     = (bf16*)(ws + off); off += (size_t)4096 * 1024 * 2;
  bf16* WqkvT  = (bf16*)(ws + off); off += (size_t)3072 * 1024 * 2;
  bf16* projT  = (bf16*)(ws + off); off += (size_t)512  * 1024 * 2;
  bf16* WoutT  = (bf16*)(ws + off); off += (size_t)1024 * 1024 * 2;
  float* phases= (float*)(ws + off); off += (size_t)4096 * 512 * 4;
  bf16* qb     = (bf16*)(ws + off); off += (size_t)4096 * 1024 * 2;
  bf16* kb     = (bf16*)(ws + off); off += (size_t)4096 * 1024 * 2;
  bf16* vb     = (bf16*)(ws + off); off += (size_t)4096 * 1024 * 2;
  bf16* attnb  = (bf16*)(ws + off); off += (size_t)4096 * 1024 * 2;

  k_convert<<<4096, 256, 0, stream>>>(x, xb, 1048576);
  k_convert<<<4096, 256, 0, stream>>>(p, pb, 1048576);
  k_transpose<<<dim3(48, 16), 256, 0, stream>>>(Wqkv, WqkvT, 1024, 3072);
  k_transpose<<<dim3(8, 16),  256, 0, stream>>>(proj, projT, 1024, 512);
  k_transpose<<<dim3(16, 16), 256, 0, stream>>>(Wout, WoutT, 1024, 1024);

  k_gemm128<<<dim3(32, 4), 256, 0, stream>>>(pb, projT, nullptr, phases, 4096, 512, 1024);
  k_gemm_qkv256<<<dim3(16, 12), 512, 0, stream>>>(xb, WqkvT, bqkv, phases, qb, kb, vb);

  k_flash_attn5<<<1024, 256, 0, stream>>>(qb, kb, vb, attnb);

  k_gemm128<<<dim3(32, 8), 256, 0, stream>>>(attnb, WoutT, bout, out, 4096, 1024, 1024);
}

// Round 8
// 133.193 us; speedup vs baseline: 1.4554x; 1.2195x over previous
//
#include <hip/hip_runtime.h>

// FlashCRA on MI355X — round 8:
//  - out/phase GEMMs -> k_gemm128x8: 128x128 tile, 8 waves, dbuf spread-issue staging
//    (qkv256's proven pattern at 128^2), XOR swizzle, 1 barrier/tile.
//  - attn v5 + deferred lsum reduction (single shfl at end).
//  - converts merged (1 launch), transposes merged (1 launch).
//  - qkv256 unchanged.

typedef __bf16 bf16;
typedef __bf16 bf16x8 __attribute__((ext_vector_type(8)));
typedef __bf16 bf16x4 __attribute__((ext_vector_type(4)));
typedef float f32x4 __attribute__((ext_vector_type(4)));
typedef float f32x16 __attribute__((ext_vector_type(16)));
typedef unsigned int u32;

__device__ __forceinline__ bf16 f2bf(float f) {
  unsigned u = __builtin_bit_cast(unsigned, f);
  u += 0x7FFFu + ((u >> 16) & 1u);            // RNE, inputs finite
  unsigned short h = (unsigned short)(u >> 16);
  return __builtin_bit_cast(bf16, h);
}

__device__ __forceinline__ void gload_lds16(const bf16* g, bf16* l) {
  __builtin_amdgcn_global_load_lds((const __attribute__((address_space(1))) u32*)(const void*)g,
                                   (__attribute__((address_space(3))) u32*)(void*)l, 16, 0, 0);
}

__device__ __forceinline__ u32 cvtpk_bf16(float lo, float hi) {
  u32 r;
  asm("v_cvt_pk_bf16_f32 %0, %1, %2" : "=v"(r) : "v"(lo), "v"(hi));
  return r;
}
__device__ __forceinline__ void perm32swap(u32& a, u32& b) {
  asm("v_permlane32_swap_b32 %0, %1" : "+v"(a), "+v"(b));
}

#if __has_builtin(__builtin_amdgcn_exp2f)
#define EXP2(x) __builtin_amdgcn_exp2f(x)
#else
#define EXP2(x) exp2f(x)
#endif

// SCALE * log2(e), folded into Q at pack time
#define QSCALE 0.18033688f

// XCD-chunked bijective remap (requires gridDim.x*gridDim.y % 8 == 0)
__device__ __forceinline__ void xcd_remap(int& bx, int& by) {
  const int nx = gridDim.x;
  const int nwg = nx * gridDim.y;
  const int lin = blockIdx.y * nx + blockIdx.x;
  const int chunk = nwg >> 3;
  const int nid = (lin & 7) * chunk + (lin >> 3);
  bx = nid % nx;
  by = nid / nx;
}

// ---------------- fused fp32 -> bf16 for x and p ----------------
__global__ __launch_bounds__(256) void k_convert2(const float* __restrict__ a, bf16* __restrict__ oa,
                                                  const float* __restrict__ b, bf16* __restrict__ ob,
                                                  int n4each) {
  int i = blockIdx.x * 256 + threadIdx.x;
  const float* in = a; bf16* out = oa;
  if (i >= n4each) { in = b; out = ob; i -= n4each; }
  const float4 v = ((const float4*)in)[i];
  bf16x4 o;
  o[0] = f2bf(v.x); o[1] = f2bf(v.y); o[2] = f2bf(v.z); o[3] = f2bf(v.w);
  *(bf16x4*)(out + (size_t)i * 4) = o;
}

// ---------------- fused transpose of the 3 weight matrices (all R=1024) ----------------
__global__ __launch_bounds__(256) void k_transpose3(const float* __restrict__ W1, bf16* __restrict__ O1,
                                                    const float* __restrict__ W2, bf16* __restrict__ O2,
                                                    const float* __restrict__ W3, bf16* __restrict__ O3) {
  __shared__ float t[64][65];
  int bx = blockIdx.x;
  const float* in; bf16* out; int C;
  if (bx < 48)      { in = W1; out = O1; C = 3072; }
  else if (bx < 56) { in = W2; out = O2; C = 512;  bx -= 48; }
  else              { in = W3; out = O3; C = 1024; bx -= 56; }
  const int R = 1024;
  const int c0 = bx * 64, r0 = blockIdx.y * 64;
  for (int e = threadIdx.x; e < 4096; e += 256) {
    int r = e >> 6, c = e & 63;
    t[r][c] = in[(size_t)(r0 + r) * C + c0 + c];
  }
  __syncthreads();
  for (int e = threadIdx.x; e < 4096; e += 256) {
    int c = e >> 6, r = e & 63;
    out[(size_t)(c0 + c) * R + r0 + r] = f2bf(t[r][c]);
  }
}

// ---------------- C[M][N] = A @ Bt^T + bias — 128^2, 8 waves, spread-issue dbuf ----------------
// 512 thr = 8 waves (2M x 4N); per-wave 64x32 = acc[4][2]. LDS 64KB (A/B dbuf 128x64).
// Stages for tile kt+1 issued inside kt's two kk-phases; one barrier per K-tile.
__global__ __launch_bounds__(512, 2) void k_gemm128x8(const bf16* __restrict__ A,
                                                      const bf16* __restrict__ Bt,
                                                      const float* __restrict__ bias,
                                                      float* __restrict__ C,
                                                      int M, int N, int K) {
  __shared__ bf16 sA0[8192], sA1[8192];       // 128 x 64 each
  __shared__ bf16 sB0[8192], sB1[8192];
  const int tid = threadIdx.x;
  const int lane = tid & 63, w = tid >> 6;
  const int lrow = lane & 15, lgrp = lane >> 4;
  const int wm = (w >> 2) * 64, wn = (w & 3) * 32;
  int bx, by;
  xcd_remap(bx, by);
  const int m0 = bx * 128, n0 = by * 128;
  const int rsub = lane >> 3, slot = lane & 7;
  const int swz8 = (slot ^ rsub) * 8;         // pre-swizzled global 16B slot
  const int r7 = lrow & 7;                    // ds_read swizzle key
  const int nkt = K >> 6;

  const bf16* Ab = A  + (size_t)m0 * K;
  const bf16* Bb = Bt + (size_t)n0 * K;

  f32x4 acc[4][2] = {};

  // prologue: stage tile 0 (wave w covers rows c*64 + w*8 + rsub)
#pragma unroll
  for (int c = 0; c < 2; ++c) {
    gload_lds16(Ab + (size_t)(c * 64 + w * 8 + rsub) * K + swz8, sA0 + c * 4096 + w * 512);
    gload_lds16(Bb + (size_t)(c * 64 + w * 8 + rsub) * K + swz8, sB0 + c * 4096 + w * 512);
  }
  __syncthreads();

  for (int kt = 0; kt < nkt; ++kt) {
    const bf16* pA = (kt & 1) ? sA1 : sA0;
    const bf16* pB = (kt & 1) ? sB1 : sB0;
    bf16* nA = (kt & 1) ? sA0 : sA1;
    bf16* nB = (kt & 1) ? sB0 : sB1;
    const size_t knext = (size_t)(kt + 1) * 64;
    const bool more = (kt < nkt - 1);

#pragma unroll
    for (int kk = 0; kk < 2; ++kk) {
      bf16x8 af[4], bfr[2];
#pragma unroll
      for (int mi = 0; mi < 4; ++mi)
        af[mi] = *(const bf16x8*)&pA[(wm + mi * 16 + lrow) * 64 + ((kk * 4 + lgrp) ^ r7) * 8];
#pragma unroll
      for (int ni = 0; ni < 2; ++ni)
        bfr[ni] = *(const bf16x8*)&pB[(wn + ni * 16 + lrow) * 64 + ((kk * 4 + lgrp) ^ r7) * 8];
      if (more) {
        // kk=0: stage next A; kk=1: stage next B (spread across the tile's compute)
        const bf16* src = kk ? Bb : Ab;
        bf16* dst = kk ? nB : nA;
#pragma unroll
        for (int c = 0; c < 2; ++c)
          gload_lds16(src + (size_t)(c * 64 + w * 8 + rsub) * K + knext + swz8, dst + c * 4096 + w * 512);
      }
      __builtin_amdgcn_s_setprio(1);
#pragma unroll
      for (int mi = 0; mi < 4; ++mi)
#pragma unroll
        for (int ni = 0; ni < 2; ++ni)
          acc[mi][ni] = __builtin_amdgcn_mfma_f32_16x16x32_bf16(af[mi], bfr[ni], acc[mi][ni], 0, 0, 0);
      __builtin_amdgcn_s_setprio(0);
    }
    __syncthreads();   // next tile staged + WAR ordering for the swap
  }

#pragma unroll
  for (int mi = 0; mi < 4; ++mi)
#pragma unroll
    for (int ni = 0; ni < 2; ++ni) {
      const int col = n0 + wn + ni * 16 + lrow;
      const float bv = bias ? bias[col] : 0.f;
#pragma unroll
      for (int j = 0; j < 4; ++j) {
        const int row = m0 + wm + mi * 16 + lgrp * 4 + j;
        C[(size_t)row * N + col] = acc[mi][ni][j] + bv;
      }
    }
}

// ---------------- QKV GEMM, 256x256 tile, spread-issue staging + fused rotate ----------------
__global__ __launch_bounds__(512, 2) void k_gemm_qkv256(const bf16* __restrict__ A,
                                                        const bf16* __restrict__ Bt,
                                                        const float* __restrict__ bqkv,
                                                        const float* __restrict__ phases,
                                                        bf16* __restrict__ qb,
                                                        bf16* __restrict__ kb,
                                                        bf16* __restrict__ vb) {
  __shared__ bf16 sA0[16384], sA1[16384];     // 256 x 64 each
  __shared__ bf16 sB0[16384], sB1[16384];
  const int tid = threadIdx.x;
  const int lane = tid & 63, w = tid >> 6;
  const int lrow = lane & 15, lgrp = lane >> 4;
  const int wm = (w >> 2) * 128;              // wave M offset: 0 / 128
  const int wn = (w & 3) * 64;                // wave N offset: 0..192
  const int m0 = blockIdx.x * 256, n0 = blockIdx.y * 256;
  const int K = 1024;

  const int srow = tid >> 3;                  // 0..63
  const int swz8 = (((tid & 7) ^ (srow & 7))) * 8;
  const int r7 = lrow & 7;

  const bf16* Ab = A  + (size_t)m0 * K;
  const bf16* Bb = Bt + (size_t)n0 * K;

  f32x4 acc[8][4] = {};

#pragma unroll
  for (int g = 0; g < 4; ++g) {
    gload_lds16(Ab + (size_t)(g * 64 + srow) * K + swz8, sA0 + g * 4096 + w * 512);
    gload_lds16(Bb + (size_t)(g * 64 + srow) * K + swz8, sB0 + g * 4096 + w * 512);
  }
  __syncthreads();

  for (int kt = 0; kt < 16; ++kt) {
    const bf16* pA = (kt & 1) ? sA1 : sA0;
    const bf16* pB = (kt & 1) ? sB1 : sB0;
    bf16* nA = (kt & 1) ? sA0 : sA1;
    bf16* nB = (kt & 1) ? sB0 : sB1;
    const size_t knext = (size_t)(kt + 1) * 64;

    bf16x8 bfr[4][2];
#pragma unroll
    for (int ni = 0; ni < 4; ++ni)
#pragma unroll
      for (int kk = 0; kk < 2; ++kk)
        bfr[ni][kk] = *(const bf16x8*)&pB[(wn + ni * 16 + lrow) * 64 + ((kk * 4 + lgrp) ^ r7) * 8];

#pragma unroll
    for (int q = 0; q < 4; ++q) {
      if (kt < 15) {
        gload_lds16(Ab + (size_t)(q * 64 + srow) * K + knext + swz8, nA + q * 4096 + w * 512);
        gload_lds16(Bb + (size_t)(q * 64 + srow) * K + knext + swz8, nB + q * 4096 + w * 512);
      }
      bf16x8 af[2][2];
#pragma unroll
      for (int m2 = 0; m2 < 2; ++m2)
#pragma unroll
        for (int kk = 0; kk < 2; ++kk)
          af[m2][kk] = *(const bf16x8*)&pA[(wm + (q * 2 + m2) * 16 + lrow) * 64 + ((kk * 4 + lgrp) ^ r7) * 8];
      __builtin_amdgcn_s_setprio(1);
#pragma unroll
      for (int m2 = 0; m2 < 2; ++m2)
#pragma unroll
        for (int ni = 0; ni < 4; ++ni)
#pragma unroll
          for (int kk = 0; kk < 2; ++kk)
            acc[q * 2 + m2][ni] =
                __builtin_amdgcn_mfma_f32_16x16x32_bf16(af[m2][kk], bfr[ni][kk], acc[q * 2 + m2][ni], 0, 0, 0);
      __builtin_amdgcn_s_setprio(0);
    }
    __syncthreads();
  }

  // ---- fused epilogue: bias + rotate + pack ----
  const int nw = n0 + wn;
  const int sec = nw >> 10;          // 0=q, 1=k, 2=v
  const int hh = (nw & 1023) >> 6;
  const float b0 = bqkv[nw + lrow];
  const float b1 = bqkv[nw + 16 + lrow];
  const float b2 = bqkv[nw + 32 + lrow];
  const float b3 = bqkv[nw + 48 + lrow];

  if (sec == 2) {
#pragma unroll
    for (int mi = 0; mi < 8; ++mi) {
      const int row0 = m0 + wm + mi * 16 + lgrp * 4;
      const int b = row0 >> 11, l0 = row0 & 2047;
#pragma unroll
      for (int ni = 0; ni < 4; ++ni) {
        const int d = ni * 16 + lrow;
        const float bv = (ni == 0) ? b0 : (ni == 1) ? b1 : (ni == 2) ? b2 : b3;
        bf16x4 pv;
#pragma unroll
        for (int j = 0; j < 4; ++j) pv[j] = f2bf(acc[mi][ni][j] + bv);
        *(bf16x4*)&vb[(((size_t)(b * 16 + hh)) * 64 + d) * 2048 + l0] = pv;
      }
    }
  } else {
    bf16* qk = sec ? kb : qb;
    const float qs = sec ? 1.0f : QSCALE;
#pragma unroll
    for (int mi = 0; mi < 8; ++mi) {
#pragma unroll
      for (int j = 0; j < 4; ++j) {
        const int row = m0 + wm + mi * 16 + lgrp * 4 + j;
        const int b = row >> 11, l = row & 2047;
        const float ph1 = phases[(size_t)row * 512 + hh * 32 + lrow];
        const float ph2 = phases[(size_t)row * 512 + hh * 32 + 16 + lrow];
        float s1, c1, s2, c2;
        __sincosf(ph1, &s1, &c1);
        __sincosf(ph2, &s2, &c2);
        const float t0 = acc[mi][0][j] + b0;
        const float t1 = acc[mi][1][j] + b1;
        const float t2 = acc[mi][2][j] + b2;
        const float t3 = acc[mi][3][j] + b3;
        bf16* base = qk + (((size_t)(b * 16 + hh)) * 2048 + l) * 64;
        base[lrow]      = f2bf((t0 * c1 - t2 * s1) * qs);
        base[16 + lrow] = f2bf((t1 * c2 - t3 * s2) * qs);
        base[32 + lrow] = f2bf((t0 * s1 + t2 * c1) * qs);
        base[48 + lrow] = f2bf((t1 * s2 + t3 * c2) * qs);
      }
    }
  }
}

// ---------------- flash attention (v5 + deferred lsum reduction) ----------------
__global__ __launch_bounds__(256, 4) void k_flash_attn5(const bf16* __restrict__ qb,
                                                        const bf16* __restrict__ kb,
                                                        const bf16* __restrict__ vb,
                                                        bf16* __restrict__ attnout) {
  const int tid = threadIdx.x, lane = tid & 63, w = tid >> 6;
  const int ql = lane & 31, hi = lane >> 5;
  const int tsel = w >> 1;                    // kv half of tile
  const int qh = w & 1;                       // q half (32 rows)
  const int fid = blockIdx.x;
  const int nid = (fid & 7) * 128 + (fid >> 3);
  const int qblk = nid & 31, h = (nid >> 5) & 15, b = nid >> 9;
  const size_t bh = (size_t)b * 16 + h;
  const bf16* Kp = kb + bh * 2048 * 64;
  const bf16* Vp = vb + bh * 64 * 2048;

  __shared__ __align__(16) char smem[32768];
  bf16* sK = (bf16*)smem;                     // [2][64*64] double-buffered
  bf16* sV = (bf16*)(smem + 16384);

  const bf16* Qp = qb + (bh * 2048 + (size_t)qblk * 64 + qh * 32 + ql) * 64;
  bf16x8 qf[4];
#pragma unroll
  for (int c = 0; c < 4; ++c) qf[c] = *(const bf16x8*)(Qp + c * 16 + hi * 8);

  const int srow = tid >> 3;                  // 0..31
  const int swz = (tid & 7) ^ (srow & 7);     // pre-swizzled global 16B slot

  f32x16 o0 = {}, o1 = {};
  float lsum = 0.f;                           // lane-local; reduced once at the end

#define STAGE(BUF, KV0)                                                                       \
  do {                                                                                        \
    gload_lds16(Kp + (size_t)((KV0) + srow) * 64 + swz * 8,        sK + (BUF) * 4096 + w * 512); \
    gload_lds16(Kp + (size_t)((KV0) + srow + 32) * 64 + swz * 8,   sK + (BUF) * 4096 + 2048 + w * 512); \
    gload_lds16(Vp + (size_t)srow * 2048 + (KV0) + swz * 8,        sV + (BUF) * 4096 + w * 512); \
    gload_lds16(Vp + (size_t)(srow + 32) * 2048 + (KV0) + swz * 8, sV + (BUF) * 4096 + 2048 + w * 512); \
  } while (0)

  STAGE(0, 0);
  __syncthreads();

  for (int t = 0; t < 32; ++t) {
    const int cur = t & 1;
    if (t < 31) STAGE(cur ^ 1, (t + 1) * 64);

    const bf16* sKc = sK + cur * 4096;
    const bf16* sVc = sV + cur * 4096;

    f32x16 st0 = {};
#pragma unroll
    for (int c = 0; c < 4; ++c) {
      const int j = (c * 2 + hi) ^ (ql & 7);
      bf16x8 kf = *(const bf16x8*)&sKc[(tsel * 32 + ql) * 64 + j * 8];
      __builtin_amdgcn_s_setprio(1);
      st0 = __builtin_amdgcn_mfma_f32_32x32x16_bf16(kf, qf[c], st0, 0, 0, 0);
      __builtin_amdgcn_s_setprio(0);
    }

#pragma unroll
    for (int j2 = 0; j2 < 16; ++j2) {
      float pv = EXP2(st0[j2]);
      st0[j2] = pv; lsum += pv;
    }

#pragma unroll
    for (int fs = 0; fs < 2; ++fs) {
      u32 a0 = cvtpk_bf16(st0[fs * 8 + 0], st0[fs * 8 + 1]);
      u32 a1 = cvtpk_bf16(st0[fs * 8 + 2], st0[fs * 8 + 3]);
      u32 a2 = cvtpk_bf16(st0[fs * 8 + 4], st0[fs * 8 + 5]);
      u32 a3 = cvtpk_bf16(st0[fs * 8 + 6], st0[fs * 8 + 7]);
      perm32swap(a0, a2);
      perm32swap(a1, a3);
      union { u32 u[4]; bf16x8 v; } cu;
      cu.u[0] = a0; cu.u[1] = a1; cu.u[2] = a2; cu.u[3] = a3;
      const int j = (tsel * 4 + fs * 2 + hi) ^ (ql & 7);
      bf16x8 vf0 = *(const bf16x8*)&sVc[ql * 64 + j * 8];
      bf16x8 vf1 = *(const bf16x8*)&sVc[(32 + ql) * 64 + j * 8];
      __builtin_amdgcn_s_setprio(1);
      o0 = __builtin_amdgcn_mfma_f32_32x32x16_bf16(vf0, cu.v, o0, 0, 0, 0);
      o1 = __builtin_amdgcn_mfma_f32_32x32x16_bf16(vf1, cu.v, o1, 0, 0, 0);
      __builtin_amdgcn_s_setprio(0);
    }
    __syncthreads();
  }

  float* cb = (float*)smem;
  if (w >= 2) {
    const int idx = ((w - 2) * 64 + lane) * 34;
#pragma unroll
    for (int i = 0; i < 16; ++i) cb[idx + i] = o0[i];
#pragma unroll
    for (int i = 0; i < 16; ++i) cb[idx + 16 + i] = o1[i];
    cb[idx + 32] = lsum;
  }
  __syncthreads();
  if (w < 2) {
    const int idx = (w * 64 + lane) * 34;
#pragma unroll
    for (int i = 0; i < 16; ++i) o0[i] += cb[idx + i];
#pragma unroll
    for (int i = 0; i < 16; ++i) o1[i] += cb[idx + 16 + i];
    lsum += cb[idx + 32];
    lsum += __shfl_xor(lsum, 32);             // partner lane holds the other kv reg-half

    const float inv = 1.f / lsum;
    const int qrow = qblk * 64 + qh * 32 + ql;
    bf16* outp = attnout + ((size_t)b * 2048 + qrow) * 1024 + h * 64;
#pragma unroll
    for (int j2 = 0; j2 < 4; ++j2) {
      bf16x4 ov;
#pragma unroll
      for (int jj = 0; jj < 4; ++jj) ov[jj] = f2bf(o0[j2 * 4 + jj] * inv);
      *(bf16x4*)(outp + j2 * 8 + hi * 4) = ov;
#pragma unroll
      for (int jj = 0; jj < 4; ++jj) ov[jj] = f2bf(o1[j2 * 4 + jj] * inv);
      *(bf16x4*)(outp + 32 + j2 * 8 + hi * 4) = ov;
    }
  }
#undef STAGE
}

// ---------------- launch ----------------
extern "C" void kernel_launch(void* const* d_in, const int* in_sizes, int n_in,
                              void* d_out, int out_size, void* d_ws, size_t ws_size,
                              hipStream_t stream) {
  (void)in_sizes; (void)n_in; (void)out_size; (void)ws_size;
  const float* x    = (const float*)d_in[0];
  const float* p    = (const float*)d_in[1];
  const float* Wqkv = (const float*)d_in[2];
  const float* bqkv = (const float*)d_in[3];
  const float* Wout = (const float*)d_in[4];
  const float* bout = (const float*)d_in[5];
  const float* proj = (const float*)d_in[6];
  float* out = (float*)d_out;

  char* ws = (char*)d_ws;
  size_t off = 0;
  bf16* xb     = (bf16*)(ws + off); off += (size_t)4096 * 1024 * 2;
  bf16* pb     = (bf16*)(ws + off); off += (size_t)4096 * 1024 * 2;
  bf16* WqkvT  = (bf16*)(ws + off); off += (size_t)3072 * 1024 * 2;
  bf16* projT  = (bf16*)(ws + off); off += (size_t)512  * 1024 * 2;
  bf16* WoutT  = (bf16*)(ws + off); off += (size_t)1024 * 1024 * 2;
  float* phases= (float*)(ws + off); off += (size_t)4096 * 512 * 4;
  bf16* qb     = (bf16*)(ws + off); off += (size_t)4096 * 1024 * 2;
  bf16* kb     = (bf16*)(ws + off); off += (size_t)4096 * 1024 * 2;
  bf16* vb     = (bf16*)(ws + off); off += (size_t)4096 * 1024 * 2;
  bf16* attnb  = (bf16*)(ws + off); off += (size_t)4096 * 1024 * 2;

  k_convert2<<<8192, 256, 0, stream>>>(x, xb, p, pb, 1048576);
  k_transpose3<<<dim3(72, 16), 256, 0, stream>>>(Wqkv, WqkvT, proj, projT, Wout, WoutT);

  k_gemm128x8<<<dim3(32, 4), 512, 0, stream>>>(pb, projT, nullptr, phases, 4096, 512, 1024);
  k_gemm_qkv256<<<dim3(16, 12), 512, 0, stream>>>(xb, WqkvT, bqkv, phases, qb, kb, vb);

  k_flash_attn5<<<1024, 256, 0, stream>>>(qb, kb, vb, attnb);

  k_gemm128x8<<<dim3(32, 8), 512, 0, stream>>>(attnb, WoutT, bout, out, 4096, 1024, 1024);
}